// Round 7
// baseline (547.147 us; speedup 1.0000x reference)
//
#include <hip/hip_runtime.h>
#include <hip/hip_bf16.h>

// B=1, N_PATCH=N_TOK=512, D_MODEL=1024, HEADS=8 (dh=128), WINDOW=64 -> L=66.
// Fused single kernel v2: 256 blocks x 512 threads (8 waves; LDS 128KB -> 1 block/CU,
// co-residency guaranteed), grid barriers between phases. All GEMM-descriptor
// indices are block-uniform (scalar s_load) -- v1's divergent kernarg indexing
// caused catastrophic scratch spill (423MB HBM traffic).
#define MDIM 512
#define NDIM 1024
#define LSLOT 66
#define NBLK 256u

typedef __attribute__((ext_vector_type(8))) short short8;   // 8 bf16 = 4 VGPR
typedef __attribute__((ext_vector_type(4))) short short4v;  // 4 bf16 = 8 B
typedef __attribute__((ext_vector_type(4))) float f32x4;    // MFMA C/D
typedef __hip_bfloat16 bf16;

static __device__ __forceinline__ short f2bf(float f) {
    return __builtin_bit_cast(short, __float2bfloat16(f));
}
static __device__ __forceinline__ short8 cvt8(float4 a, float4 b) {
    short8 v;
    v[0] = f2bf(a.x); v[1] = f2bf(a.y); v[2] = f2bf(a.z); v[3] = f2bf(a.w);
    v[4] = f2bf(b.x); v[5] = f2bf(b.y); v[6] = f2bf(b.z); v[7] = f2bf(b.w);
    return v;
}
// async 16B global -> LDS DMA. LDS dest = uniform base + lane*16.
static __device__ __forceinline__ void gload16(const void* g, void* l) {
    __builtin_amdgcn_global_load_lds(
        (const __attribute__((address_space(1))) unsigned int*)g,
        (__attribute__((address_space(3))) unsigned int*)l, 16, 0, 0);
}

struct CvtDesc { const float* src; bf16* dst; int n; };
struct GDesc {
    const bf16* A;      // (512, K)
    const bf16* W;      // (1024, K)
    const float* bias;  // (1024)
    const float* res;   // optional fp32 residual or nullptr
    float* C;           // fp32 out (512,1024)
    bf16* Cb;           // optional bf16 dual-out or nullptr
    int K;              // 768 or 1024
};
struct AttnArgs { const float *Q, *K, *V, *kb, *vb; bf16* O; };
struct FusedArgs {
    CvtDesc cv[12];
    GDesc s1[2], s2[6], s4[2];
    AttnArgs at[2];
    unsigned* bar;      // 4 zero-init'd counters
};

// Device-scope grid barrier; each counter used exactly once per launch.
static __device__ __forceinline__ void grid_bar(unsigned* ctr) {
    __syncthreads();
    if (threadIdx.x == 0) {
        __threadfence();
        __hip_atomic_fetch_add(ctr, 1u, __ATOMIC_ACQ_REL, __HIP_MEMORY_SCOPE_AGENT);
        while (__hip_atomic_load(ctr, __ATOMIC_ACQUIRE, __HIP_MEMORY_SCOPE_AGENT) < NBLK)
            __builtin_amdgcn_s_sleep(2);
        __threadfence();
    }
    __syncthreads();
}

// One 64x64 output tile per 2-wave unit (w2 = wave-in-unit; w2=0 stages A, w2=1 stages W).
// 2-buf counted-vmcnt(8) pipeline, BK=64, 32KB LDS/unit. All units of a block run in
// lockstep (same K), so the block-wide s_barrier cadence matches.
// LDS swizzle (both-sides XOR, rule #21): chunk s of row r holds k-chunk s^(r&7);
// staged linear-dest with inverse-swizzled per-lane global source.
static __device__ __forceinline__ void gemm_tile(const GDesc& g, int m0, int n0,
                                                 short* L, int w2, int lane) {
    const int K = g.K;
    const size_t rowb = (size_t)K * 2;
    const char* sbase = (const char*)(w2 ? (const void*)g.W : (const void*)g.A)
                      + (size_t)(w2 ? n0 : m0) * rowb
                      + (size_t)(lane >> 3) * rowb
                      + (size_t)(((lane & 7) ^ (lane >> 3)) << 4);
    const int fr = lane & 15;
    const int fq = lane >> 4;
    const int wm = w2 * 32;
    short* Lw = L + w2 * 4096;          // this wave's staging plane (A @0, W @4096)

    f32x4 acc[2][4] = {};
    const int NT = K / 64;              // 12 or 16

    // prologue: tiles 0,1 -> bufs 0,1 (16 loads/wave in flight)
#pragma unroll
    for (int tt = 0; tt < 2; ++tt)
#pragma unroll
        for (int i = 0; i < 8; ++i)
            gload16(sbase + (size_t)tt * 128 + (size_t)i * 8 * rowb,
                    Lw + tt * 8192 + i * 512);

#define GSTEP(VMW)                                                              \
    {                                                                           \
        asm volatile("s_waitcnt vmcnt(" #VMW ")" ::: "memory");                 \
        __builtin_amdgcn_s_barrier();        /* tile t resident (all waves) */  \
        __builtin_amdgcn_sched_barrier(0);                                      \
        const int b = t & 1;                                                    \
        short8 af[2][2], wf[4][2];                                              \
        _Pragma("unroll")                                                       \
        for (int kk = 0; kk < 2; ++kk) {                                        \
            const int ch = kk * 4 + fq;                                         \
            _Pragma("unroll")                                                   \
            for (int i = 0; i < 2; ++i) {                                       \
                const int r = wm + i * 16 + fr;                                 \
                af[i][kk] = *(const short8*)&L[b * 8192 + r * 64 + ((ch ^ (r & 7)) << 3)]; \
            }                                                                   \
            _Pragma("unroll")                                                   \
            for (int j = 0; j < 4; ++j) {                                       \
                const int c = j * 16 + fr;                                      \
                wf[j][kk] = *(const short8*)&L[b * 8192 + 4096 + c * 64 + ((ch ^ (c & 7)) << 3)]; \
            }                                                                   \
        }                                                                       \
        asm volatile("s_waitcnt lgkmcnt(0)" ::: "memory");                      \
        __builtin_amdgcn_sched_barrier(0);                                      \
        __builtin_amdgcn_s_barrier();        /* all reads of buf b done */      \
        if (t + 2 < NT) {                                                       \
            const char* p = sbase + (size_t)(t + 2) * 128;                      \
            _Pragma("unroll")                                                   \
            for (int i = 0; i < 8; ++i)                                         \
                gload16(p + (size_t)i * 8 * rowb, Lw + b * 8192 + i * 512);     \
        }                                                                       \
        _Pragma("unroll")                                                       \
        for (int kk = 0; kk < 2; ++kk)                                          \
            _Pragma("unroll")                                                   \
            for (int i = 0; i < 2; ++i)                                         \
                _Pragma("unroll")                                               \
                for (int j = 0; j < 4; ++j)                                     \
                    acc[i][j] = __builtin_amdgcn_mfma_f32_16x16x32_bf16(        \
                        af[i][kk], wf[j][kk], acc[i][j], 0, 0, 0);              \
    }

    int t = 0;
    for (; t < NT - 1; ++t) GSTEP(8)    // tile t+1 stays in flight
    GSTEP(0)                            // last tile: drain
#undef GSTEP

    // epilogue: C/D layout col=lane&15, row=(lane>>4)*4+reg
#pragma unroll
    for (int i = 0; i < 2; ++i) {
        const int row0 = m0 + wm + i * 16 + fq * 4;
#pragma unroll
        for (int j = 0; j < 4; ++j) {
            const int col = n0 + j * 16 + fr;
            const float b = g.bias[col];
#pragma unroll
            for (int r = 0; r < 4; ++r) {
                float v = acc[i][j][r] + b;
                const size_t o = (size_t)(row0 + r) * NDIM + col;
                if (g.res) v += g.res[o];
                g.C[o] = v;
                if (g.Cb) g.Cb[o] = __float2bfloat16(v);
            }
        }
    }
}

__global__ __launch_bounds__(512, 2) void fused(FusedArgs fa) {
    __shared__ __align__(16) char smem[131072];   // 4 gemm units x 32KB; attn uses 125KB
    const int tid  = threadIdx.x;
    const int bi   = blockIdx.x;
    const int lane = tid & 63;
    const int wave = tid >> 6;      // 0..7
    const int unit = wave >> 1;     // 0..3
    const int w2   = wave & 1;

    // ---------------- phase 0: fp32 -> bf16 conversions ----------------
    {
        const int gtid = bi * 512 + tid;           // < 131072
#pragma unroll 1
        for (int d = 0; d < 12; ++d) {
            const CvtDesc c = fa.cv[d];
            for (int i = gtid * 8; i < c.n; i += 131072 * 8) {
                const float4 a = *(const float4*)(c.src + i);
                const float4 b = *(const float4*)(c.src + i + 4);
                *(short8*)((short*)c.dst + i) = cvt8(a, b);
            }
        }
    }
    grid_bar(fa.bar + 0);

    short* L = (short*)(smem + unit * 32768);

    // ---------------- phase 1: input projections (256 tiles on 64 blocks) ----------
    if (bi < 64) {
        const GDesc& g = fa.s1[bi >> 5];           // block-uniform (scalar)
        const int w = (bi * 4 + unit) & 127;       // tile within gemm
        gemm_tile(g, (w >> 4) * 64, (w & 15) * 64, L, w2, lane);
    }
    grid_bar(fa.bar + 1);

    // ---------------- phase 2: QKV projections (768 tiles on 192 blocks) -----------
    if (bi < 192) {
        const GDesc& g = fa.s2[bi >> 5];           // block-uniform (scalar)
        const int w = (bi * 4 + unit) & 127;
        gemm_tile(g, (w >> 4) * 64, (w & 15) * 64, L, w2, lane);
    }
    grid_bar(fa.bar + 2);

    // ---------------- phase 3: sliding-window attention (256 blocks) ---------------
    {
        const AttnArgs a = fa.at[bi >> 7];         // block-uniform
        const int h  = (bi >> 4) & 7;
        const int n0 = (bi & 15) * 32;
        float* Ks = (float*)smem;        // 97*128
        float* Vs = Ks + 12416;          // 97*128
        float* Qs = Vs + 12416;          // 32*132
        float* Ps = Qs + 4224;           // 32*68
        float* InvS = Ps + 2176;         // 32

        // stage K/V window rows wp=0..96 (ctx rows n0-32 .. n0+64); OOB -> kb/vb
        for (int i = tid; i < 97 * 32; i += 512) {
            const int wp = i >> 5, d4 = i & 31;
            const int idx = n0 - 32 + wp;
            const bool valid = (idx >= 0) && (idx < MDIM);
            const float* sk = (valid ? (a.K + (size_t)idx * NDIM) : a.kb) + h * 128;
            const float* sv = (valid ? (a.V + (size_t)idx * NDIM) : a.vb) + h * 128;
            const float4 kv = *(const float4*)(sk + d4 * 4);
            const float4 vv = *(const float4*)(sv + d4 * 4);
            const int slot = d4 ^ (wp & 31);
            *(float4*)&Ks[wp * 128 + slot * 4] = kv;
            *(float4*)&Vs[wp * 128 + slot * 4] = vv;
        }
        for (int i = tid; i < 32 * 32; i += 512) {
            const int r = i >> 5, d4 = i & 31;
            *(float4*)&Qs[r * 132 + d4 * 4] =
                *(const float4*)(a.Q + (size_t)(n0 + r) * NDIM + h * 128 + d4 * 4);
        }
        __syncthreads();

        const int r = tid >> 4, sub = tid & 15;    // 16 lanes per query row
        const int n = n0 + r;
        const int lo_inv = max(0, 32 - n);
        const int hi_inv = max(0, n - 478);
        const int n_zero = max(0, 64 - (LSLOT - lo_inv - hi_inv));
        const float scale = 0.088388347648318447f; // 1/sqrt(128)

        // scores: thread (r,sub) does dots for l = sub + 16k (k=0..4)
        float dots[5];
#pragma unroll
        for (int k = 0; k < 5; ++k) dots[k] = 0.f;
#pragma unroll
        for (int db = 0; db < 4; ++db) {
            float4 q[8];
#pragma unroll
            for (int c = 0; c < 8; ++c) q[c] = *(float4*)&Qs[r * 132 + (db * 8 + c) * 4];
            for (int k = 0; k < 5; ++k) {
                const int l = sub + 16 * k;
                if (l >= LSLOT) break;
                const int wp = r + l, key = wp & 31;
                float accd = dots[k];
#pragma unroll
                for (int c = 0; c < 8; ++c) {
                    const int d4 = db * 8 + c;
                    const float4 kv = *(float4*)&Ks[wp * 128 + (d4 ^ key) * 4];
                    accd += kv.x * q[c].x + kv.y * q[c].y + kv.z * q[c].z + kv.w * q[c].w;
                }
                dots[k] = accd;
            }
        }
        for (int k = 0; k < 5; ++k) {
            const int l = sub + 16 * k;
            if (l >= LSLOT) break;
            const int idx = n - 32 + l;
            const bool valid = (idx >= 0) && (idx < MDIM);
            bool attend = valid;
            if (!valid) {
                const int ir = (l < lo_inv) ? l : (l - (LSLOT - hi_inv));
                attend = ir < n_zero;
            }
            Ps[r * 68 + l] = attend ? dots[k] * scale : -1e30f;
        }
        __syncthreads();

        // softmax: 16 lanes per row, shfl_xor width-16 reduce
        {
            float m = -1e30f;
            for (int k = 0; k < 5; ++k) {
                const int l = sub + 16 * k;
                if (l < LSLOT) m = fmaxf(m, Ps[r * 68 + l]);
            }
            for (int s = 1; s < 16; s <<= 1) m = fmaxf(m, __shfl_xor(m, s, 64));
            float sum = 0.f;
            for (int k = 0; k < 5; ++k) {
                const int l = sub + 16 * k;
                if (l >= LSLOT) break;
                const float e = expf(Ps[r * 68 + l] - m);
                Ps[r * 68 + l] = e;
                sum += e;
            }
            for (int s = 1; s < 16; s <<= 1) sum += __shfl_xor(sum, s, 64);
            if (sub == 0) InvS[r] = 1.0f / sum;
        }
        __syncthreads();

        // PV: thread (r,sub) owns d4 chunks sub, sub+16
        float4 acc2[2] = {};
        for (int l = 0; l < LSLOT; ++l) {
            const float p = Ps[r * 68 + l];
            const int wp = r + l, key = wp & 31;
#pragma unroll
            for (int c = 0; c < 2; ++c) {
                const int d4 = sub + 16 * c;
                const float4 vv = *(float4*)&Vs[wp * 128 + (d4 ^ key) * 4];
                acc2[c].x += p * vv.x; acc2[c].y += p * vv.y;
                acc2[c].z += p * vv.z; acc2[c].w += p * vv.w;
            }
        }
        const float inv = InvS[r];
#pragma unroll
        for (int c = 0; c < 2; ++c) {
            short4v o;
            o[0] = f2bf(acc2[c].x * inv); o[1] = f2bf(acc2[c].y * inv);
            o[2] = f2bf(acc2[c].z * inv); o[3] = f2bf(acc2[c].w * inv);
            *(short4v*)((short*)a.O + (size_t)n * NDIM + h * 128 + (sub + 16 * c) * 4) = o;
        }
    }
    grid_bar(fa.bar + 3);

    // ---------------- phase 4: output projections + residual (64 blocks) -----------
    if (bi < 64) {
        const GDesc& g = fa.s4[bi >> 5];           // block-uniform
        const int w = (bi * 4 + unit) & 127;
        gemm_tile(g, (w >> 4) * 64, (w & 15) * 64, L, w2, lane);
    }
}

extern "C" void kernel_launch(void* const* d_in, const int* in_sizes, int n_in,
                              void* d_out, int out_size, void* d_ws, size_t ws_size,
                              hipStream_t stream) {
    const float* images = (const float*)d_in[0];   // (512,1024)
    const float* caps   = (const float*)d_in[1];   // (512,768)
    const float* tp_w = (const float*)d_in[3];
    const float* tp_b = (const float*)d_in[4];
    const float* ip_w = (const float*)d_in[5];
    const float* ip_b = (const float*)d_in[6];
    const float* ia_qw = (const float*)d_in[7];  const float* ia_qb = (const float*)d_in[8];
    const float* ia_kw = (const float*)d_in[9];  const float* ia_kb = (const float*)d_in[10];
    const float* ia_vw = (const float*)d_in[11]; const float* ia_vb = (const float*)d_in[12];
    const float* ia_ow = (const float*)d_in[13]; const float* ia_ob = (const float*)d_in[14];
    const float* ta_qw = (const float*)d_in[15]; const float* ta_qb = (const float*)d_in[16];
    const float* ta_kw = (const float*)d_in[17]; const float* ta_kb = (const float*)d_in[18];
    const float* ta_vw = (const float*)d_in[19]; const float* ta_vb = (const float*)d_in[20];
    const float* ta_ow = (const float*)d_in[21]; const float* ta_ob = (const float*)d_in[22];

    const size_t S = (size_t)MDIM * NDIM;          // 524288
    float* ws = (float*)d_ws;
    float* txt = ws + 0 * S;
    float* img = ws + 1 * S;
    float* Qi  = ws + 2 * S;
    float* Ki  = ws + 3 * S;
    float* Vi  = ws + 4 * S;
    float* Qt  = ws + 5 * S;
    float* Kt  = ws + 6 * S;
    float* Vt  = ws + 7 * S;
    bf16* bb     = (bf16*)(ws + 8 * S);
    bf16* capsb  = bb;               // 512*768
    bf16* imgsb  = capsb + 393216;   // 512*1024
    bf16* txtb   = imgsb + S;
    bf16* imgb   = txtb + S;
    bf16* Oib    = imgb + S;
    bf16* Otb    = Oib + S;
    bf16* tp_wb  = Otb + S;          // 1024*768
    bf16* ip_wb  = tp_wb + 786432;
    bf16* qwb[8];
    { bf16* p = ip_wb + 1048576;
      for (int i = 0; i < 8; ++i) { qwb[i] = p; p += 1048576; } }

    float* fused_img = (float*)d_out;
    float* fused_txt = (float*)d_out + S;

    // barrier counters far past used workspace (~43 MB used)
    unsigned* bar = (unsigned*)((char*)d_ws + (64u << 20));

    FusedArgs fa = {};
    fa.cv[0]  = {caps,   capsb, 393216};
    fa.cv[1]  = {images, imgsb, (int)S};
    fa.cv[2]  = {tp_w,   tp_wb, 786432};
    fa.cv[3]  = {ip_w,   ip_wb, 1048576};
    fa.cv[4]  = {ia_qw, qwb[0], 1048576};
    fa.cv[5]  = {ia_kw, qwb[1], 1048576};
    fa.cv[6]  = {ia_vw, qwb[2], 1048576};
    fa.cv[7]  = {ia_ow, qwb[3], 1048576};
    fa.cv[8]  = {ta_qw, qwb[4], 1048576};
    fa.cv[9]  = {ta_kw, qwb[5], 1048576};
    fa.cv[10] = {ta_vw, qwb[6], 1048576};
    fa.cv[11] = {ta_ow, qwb[7], 1048576};

    fa.s1[0] = {capsb, tp_wb, tp_b, nullptr, txt, txtb, 768};
    fa.s1[1] = {imgsb, ip_wb, ip_b, nullptr, img, imgb, 1024};

    fa.s2[0] = {imgb, qwb[0], ia_qb, nullptr, Qi, nullptr, 1024};
    fa.s2[1] = {txtb, qwb[1], ia_kb, nullptr, Ki, nullptr, 1024};
    fa.s2[2] = {txtb, qwb[2], ia_vb, nullptr, Vi, nullptr, 1024};
    fa.s2[3] = {txtb, qwb[4], ta_qb, nullptr, Qt, nullptr, 1024};
    fa.s2[4] = {imgb, qwb[5], ta_kb, nullptr, Kt, nullptr, 1024};
    fa.s2[5] = {imgb, qwb[6], ta_vb, nullptr, Vt, nullptr, 1024};

    fa.at[0] = {Qi, Ki, Vi, ia_kb, ia_vb, Oib};
    fa.at[1] = {Qt, Kt, Vt, ta_kb, ta_vb, Otb};

    fa.s4[0] = {Oib, qwb[3], ia_ob, img, fused_img, nullptr, 1024};
    fa.s4[1] = {Otb, qwb[7], ta_ob, txt, fused_txt, nullptr, 1024};

    fa.bar = bar;

    hipMemsetAsync(bar, 0, 64, stream);
    fused<<<dim3(NBLK), dim3(512), 0, stream>>>(fa);
}

// Round 8
// 391.487 us; speedup vs baseline: 1.3976x; 1.3976x over previous
//
#include <hip/hip_runtime.h>
#include <hip/hip_bf16.h>

// B=1, N_PATCH=N_TOK=512, D_MODEL=1024, HEADS=8 (dh=128), WINDOW=64 -> L=66.
// Fused single kernel v3: identical to v2 except the grid barrier.
// v1/v2's barrier spun on an ACQUIRE atomic load -> per-iteration buffer_inv sc1
// (L2 invalidation storm on every XCD: 433MB junk HBM traffic, ~500us).
// v3 spins RELAXED and issues exactly one release fence before the arrive-add
// and one acquire fence after the spin exits.
#define MDIM 512
#define NDIM 1024
#define LSLOT 66
#define NBLK 256u

typedef __attribute__((ext_vector_type(8))) short short8;   // 8 bf16 = 4 VGPR
typedef __attribute__((ext_vector_type(4))) short short4v;  // 4 bf16 = 8 B
typedef __attribute__((ext_vector_type(4))) float f32x4;    // MFMA C/D
typedef __hip_bfloat16 bf16;

static __device__ __forceinline__ short f2bf(float f) {
    return __builtin_bit_cast(short, __float2bfloat16(f));
}
static __device__ __forceinline__ short8 cvt8(float4 a, float4 b) {
    short8 v;
    v[0] = f2bf(a.x); v[1] = f2bf(a.y); v[2] = f2bf(a.z); v[3] = f2bf(a.w);
    v[4] = f2bf(b.x); v[5] = f2bf(b.y); v[6] = f2bf(b.z); v[7] = f2bf(b.w);
    return v;
}
// async 16B global -> LDS DMA. LDS dest = uniform base + lane*16.
static __device__ __forceinline__ void gload16(const void* g, void* l) {
    __builtin_amdgcn_global_load_lds(
        (const __attribute__((address_space(1))) unsigned int*)g,
        (__attribute__((address_space(3))) unsigned int*)l, 16, 0, 0);
}

struct CvtDesc { const float* src; bf16* dst; int n; };
struct GDesc {
    const bf16* A;      // (512, K)
    const bf16* W;      // (1024, K)
    const float* bias;  // (1024)
    const float* res;   // optional fp32 residual or nullptr
    float* C;           // fp32 out (512,1024)
    bf16* Cb;           // optional bf16 dual-out or nullptr
    int K;              // 768 or 1024
};
struct AttnArgs { const float *Q, *K, *V, *kb, *vb; bf16* O; };
struct FusedArgs {
    CvtDesc cv[12];
    GDesc s1[2], s2[6], s4[2];
    AttnArgs at[2];
    unsigned* bar;      // 4 zero-init'd counters
};

// Device-scope grid barrier; each counter used exactly once per launch.
// RELAXED spin (global_load sc1, NO per-iteration buffer_inv); one release
// fence before arrive, one acquire fence after exit.
static __device__ __forceinline__ void grid_bar(unsigned* ctr) {
    __syncthreads();
    if (threadIdx.x == 0) {
        __threadfence();   // release: publish this block's writes to MALL
        __hip_atomic_fetch_add(ctr, 1u, __ATOMIC_RELAXED, __HIP_MEMORY_SCOPE_AGENT);
        while (__hip_atomic_load(ctr, __ATOMIC_RELAXED, __HIP_MEMORY_SCOPE_AGENT) < NBLK)
            __builtin_amdgcn_s_sleep(8);
        __threadfence();   // acquire: drop stale local cache lines (one inv)
    }
    __syncthreads();
}

// One 64x64 output tile per 2-wave unit (w2 = wave-in-unit; w2=0 stages A, w2=1 stages W).
// 2-buf counted-vmcnt(8) pipeline, BK=64, 32KB LDS/unit. All units of a block run in
// lockstep (same K), so the block-wide s_barrier cadence matches.
// LDS swizzle (both-sides XOR, rule #21): chunk s of row r holds k-chunk s^(r&7);
// staged linear-dest with inverse-swizzled per-lane global source.
static __device__ __forceinline__ void gemm_tile(const GDesc& g, int m0, int n0,
                                                 short* L, int w2, int lane) {
    const int K = g.K;
    const size_t rowb = (size_t)K * 2;
    const char* sbase = (const char*)(w2 ? (const void*)g.W : (const void*)g.A)
                      + (size_t)(w2 ? n0 : m0) * rowb
                      + (size_t)(lane >> 3) * rowb
                      + (size_t)(((lane & 7) ^ (lane >> 3)) << 4);
    const int fr = lane & 15;
    const int fq = lane >> 4;
    const int wm = w2 * 32;
    short* Lw = L + w2 * 4096;          // this wave's staging plane (A @0, W @4096)

    f32x4 acc[2][4] = {};
    const int NT = K / 64;              // 12 or 16

    // prologue: tiles 0,1 -> bufs 0,1 (16 loads/wave in flight)
#pragma unroll
    for (int tt = 0; tt < 2; ++tt)
#pragma unroll
        for (int i = 0; i < 8; ++i)
            gload16(sbase + (size_t)tt * 128 + (size_t)i * 8 * rowb,
                    Lw + tt * 8192 + i * 512);

#define GSTEP(VMW)                                                              \
    {                                                                           \
        asm volatile("s_waitcnt vmcnt(" #VMW ")" ::: "memory");                 \
        __builtin_amdgcn_s_barrier();        /* tile t resident (all waves) */  \
        __builtin_amdgcn_sched_barrier(0);                                      \
        const int b = t & 1;                                                    \
        short8 af[2][2], wf[4][2];                                              \
        _Pragma("unroll")                                                       \
        for (int kk = 0; kk < 2; ++kk) {                                        \
            const int ch = kk * 4 + fq;                                         \
            _Pragma("unroll")                                                   \
            for (int i = 0; i < 2; ++i) {                                       \
                const int r = wm + i * 16 + fr;                                 \
                af[i][kk] = *(const short8*)&L[b * 8192 + r * 64 + ((ch ^ (r & 7)) << 3)]; \
            }                                                                   \
            _Pragma("unroll")                                                   \
            for (int j = 0; j < 4; ++j) {                                       \
                const int c = j * 16 + fr;                                      \
                wf[j][kk] = *(const short8*)&L[b * 8192 + 4096 + c * 64 + ((ch ^ (c & 7)) << 3)]; \
            }                                                                   \
        }                                                                       \
        asm volatile("s_waitcnt lgkmcnt(0)" ::: "memory");                      \
        __builtin_amdgcn_sched_barrier(0);                                      \
        __builtin_amdgcn_s_barrier();        /* all reads of buf b done */      \
        if (t + 2 < NT) {                                                       \
            const char* p = sbase + (size_t)(t + 2) * 128;                      \
            _Pragma("unroll")                                                   \
            for (int i = 0; i < 8; ++i)                                         \
                gload16(p + (size_t)i * 8 * rowb, Lw + b * 8192 + i * 512);     \
        }                                                                       \
        _Pragma("unroll")                                                       \
        for (int kk = 0; kk < 2; ++kk)                                          \
            _Pragma("unroll")                                                   \
            for (int i = 0; i < 2; ++i)                                         \
                _Pragma("unroll")                                               \
                for (int j = 0; j < 4; ++j)                                     \
                    acc[i][j] = __builtin_amdgcn_mfma_f32_16x16x32_bf16(        \
                        af[i][kk], wf[j][kk], acc[i][j], 0, 0, 0);              \
    }

    int t = 0;
    for (; t < NT - 1; ++t) GSTEP(8)    // tile t+1 stays in flight
    GSTEP(0)                            // last tile: drain
#undef GSTEP

    // epilogue: C/D layout col=lane&15, row=(lane>>4)*4+reg
#pragma unroll
    for (int i = 0; i < 2; ++i) {
        const int row0 = m0 + wm + i * 16 + fq * 4;
#pragma unroll
        for (int j = 0; j < 4; ++j) {
            const int col = n0 + j * 16 + fr;
            const float b = g.bias[col];
#pragma unroll
            for (int r = 0; r < 4; ++r) {
                float v = acc[i][j][r] + b;
                const size_t o = (size_t)(row0 + r) * NDIM + col;
                if (g.res) v += g.res[o];
                g.C[o] = v;
                if (g.Cb) g.Cb[o] = __float2bfloat16(v);
            }
        }
    }
}

__global__ __launch_bounds__(512, 2) void fused(FusedArgs fa) {
    __shared__ __align__(16) char smem[131072];   // 4 gemm units x 32KB; attn uses 125KB
    const int tid  = threadIdx.x;
    const int bi   = blockIdx.x;
    const int lane = tid & 63;
    const int wave = tid >> 6;      // 0..7
    const int unit = wave >> 1;     // 0..3
    const int w2   = wave & 1;

    // ---------------- phase 0: fp32 -> bf16 conversions ----------------
    {
        const int gtid = bi * 512 + tid;           // < 131072
#pragma unroll 1
        for (int d = 0; d < 12; ++d) {
            const CvtDesc c = fa.cv[d];
            for (int i = gtid * 8; i < c.n; i += 131072 * 8) {
                const float4 a = *(const float4*)(c.src + i);
                const float4 b = *(const float4*)(c.src + i + 4);
                *(short8*)((short*)c.dst + i) = cvt8(a, b);
            }
        }
    }
    grid_bar(fa.bar + 0);

    short* L = (short*)(smem + unit * 32768);

    // ---------------- phase 1: input projections (256 tiles on 64 blocks) ----------
    if (bi < 64) {
        const GDesc& g = fa.s1[bi >> 5];           // block-uniform (scalar)
        const int w = (bi * 4 + unit) & 127;       // tile within gemm
        gemm_tile(g, (w >> 4) * 64, (w & 15) * 64, L, w2, lane);
    }
    grid_bar(fa.bar + 1);

    // ---------------- phase 2: QKV projections (768 tiles on 192 blocks) -----------
    if (bi < 192) {
        const GDesc& g = fa.s2[bi >> 5];           // block-uniform (scalar)
        const int w = (bi * 4 + unit) & 127;
        gemm_tile(g, (w >> 4) * 64, (w & 15) * 64, L, w2, lane);
    }
    grid_bar(fa.bar + 2);

    // ---------------- phase 3: sliding-window attention (256 blocks) ---------------
    {
        const AttnArgs a = fa.at[bi >> 7];         // block-uniform
        const int h  = (bi >> 4) & 7;
        const int n0 = (bi & 15) * 32;
        float* Ks = (float*)smem;        // 97*128
        float* Vs = Ks + 12416;          // 97*128
        float* Qs = Vs + 12416;          // 32*132
        float* Ps = Qs + 4224;           // 32*68
        float* InvS = Ps + 2176;         // 32

        // stage K/V window rows wp=0..96 (ctx rows n0-32 .. n0+64); OOB -> kb/vb
        for (int i = tid; i < 97 * 32; i += 512) {
            const int wp = i >> 5, d4 = i & 31;
            const int idx = n0 - 32 + wp;
            const bool valid = (idx >= 0) && (idx < MDIM);
            const float* sk = (valid ? (a.K + (size_t)idx * NDIM) : a.kb) + h * 128;
            const float* sv = (valid ? (a.V + (size_t)idx * NDIM) : a.vb) + h * 128;
            const float4 kv = *(const float4*)(sk + d4 * 4);
            const float4 vv = *(const float4*)(sv + d4 * 4);
            const int slot = d4 ^ (wp & 31);
            *(float4*)&Ks[wp * 128 + slot * 4] = kv;
            *(float4*)&Vs[wp * 128 + slot * 4] = vv;
        }
        for (int i = tid; i < 32 * 32; i += 512) {
            const int r = i >> 5, d4 = i & 31;
            *(float4*)&Qs[r * 132 + d4 * 4] =
                *(const float4*)(a.Q + (size_t)(n0 + r) * NDIM + h * 128 + d4 * 4);
        }
        __syncthreads();

        const int r = tid >> 4, sub = tid & 15;    // 16 lanes per query row
        const int n = n0 + r;
        const int lo_inv = max(0, 32 - n);
        const int hi_inv = max(0, n - 478);
        const int n_zero = max(0, 64 - (LSLOT - lo_inv - hi_inv));
        const float scale = 0.088388347648318447f; // 1/sqrt(128)

        // scores: thread (r,sub) does dots for l = sub + 16k (k=0..4)
        float dots[5];
#pragma unroll
        for (int k = 0; k < 5; ++k) dots[k] = 0.f;
#pragma unroll
        for (int db = 0; db < 4; ++db) {
            float4 q[8];
#pragma unroll
            for (int c = 0; c < 8; ++c) q[c] = *(float4*)&Qs[r * 132 + (db * 8 + c) * 4];
            for (int k = 0; k < 5; ++k) {
                const int l = sub + 16 * k;
                if (l >= LSLOT) break;
                const int wp = r + l, key = wp & 31;
                float accd = dots[k];
#pragma unroll
                for (int c = 0; c < 8; ++c) {
                    const int d4 = db * 8 + c;
                    const float4 kv = *(float4*)&Ks[wp * 128 + (d4 ^ key) * 4];
                    accd += kv.x * q[c].x + kv.y * q[c].y + kv.z * q[c].z + kv.w * q[c].w;
                }
                dots[k] = accd;
            }
        }
        for (int k = 0; k < 5; ++k) {
            const int l = sub + 16 * k;
            if (l >= LSLOT) break;
            const int idx = n - 32 + l;
            const bool valid = (idx >= 0) && (idx < MDIM);
            bool attend = valid;
            if (!valid) {
                const int ir = (l < lo_inv) ? l : (l - (LSLOT - hi_inv));
                attend = ir < n_zero;
            }
            Ps[r * 68 + l] = attend ? dots[k] * scale : -1e30f;
        }
        __syncthreads();

        // softmax: 16 lanes per row, shfl_xor width-16 reduce
        {
            float m = -1e30f;
            for (int k = 0; k < 5; ++k) {
                const int l = sub + 16 * k;
                if (l < LSLOT) m = fmaxf(m, Ps[r * 68 + l]);
            }
            for (int s = 1; s < 16; s <<= 1) m = fmaxf(m, __shfl_xor(m, s, 64));
            float sum = 0.f;
            for (int k = 0; k < 5; ++k) {
                const int l = sub + 16 * k;
                if (l >= LSLOT) break;
                const float e = expf(Ps[r * 68 + l] - m);
                Ps[r * 68 + l] = e;
                sum += e;
            }
            for (int s = 1; s < 16; s <<= 1) sum += __shfl_xor(sum, s, 64);
            if (sub == 0) InvS[r] = 1.0f / sum;
        }
        __syncthreads();

        // PV: thread (r,sub) owns d4 chunks sub, sub+16
        float4 acc2[2] = {};
        for (int l = 0; l < LSLOT; ++l) {
            const float p = Ps[r * 68 + l];
            const int wp = r + l, key = wp & 31;
#pragma unroll
            for (int c = 0; c < 2; ++c) {
                const int d4 = sub + 16 * c;
                const float4 vv = *(float4*)&Vs[wp * 128 + (d4 ^ key) * 4];
                acc2[c].x += p * vv.x; acc2[c].y += p * vv.y;
                acc2[c].z += p * vv.z; acc2[c].w += p * vv.w;
            }
        }
        const float inv = InvS[r];
#pragma unroll
        for (int c = 0; c < 2; ++c) {
            short4v o;
            o[0] = f2bf(acc2[c].x * inv); o[1] = f2bf(acc2[c].y * inv);
            o[2] = f2bf(acc2[c].z * inv); o[3] = f2bf(acc2[c].w * inv);
            *(short4v*)((short*)a.O + (size_t)n * NDIM + h * 128 + (sub + 16 * c) * 4) = o;
        }
    }
    grid_bar(fa.bar + 3);

    // ---------------- phase 4: output projections + residual (64 blocks) -----------
    if (bi < 64) {
        const GDesc& g = fa.s4[bi >> 5];           // block-uniform
        const int w = (bi * 4 + unit) & 127;
        gemm_tile(g, (w >> 4) * 64, (w & 15) * 64, L, w2, lane);
    }
}

extern "C" void kernel_launch(void* const* d_in, const int* in_sizes, int n_in,
                              void* d_out, int out_size, void* d_ws, size_t ws_size,
                              hipStream_t stream) {
    const float* images = (const float*)d_in[0];   // (512,1024)
    const float* caps   = (const float*)d_in[1];   // (512,768)
    const float* tp_w = (const float*)d_in[3];
    const float* tp_b = (const float*)d_in[4];
    const float* ip_w = (const float*)d_in[5];
    const float* ip_b = (const float*)d_in[6];
    const float* ia_qw = (const float*)d_in[7];  const float* ia_qb = (const float*)d_in[8];
    const float* ia_kw = (const float*)d_in[9];  const float* ia_kb = (const float*)d_in[10];
    const float* ia_vw = (const float*)d_in[11]; const float* ia_vb = (const float*)d_in[12];
    const float* ia_ow = (const float*)d_in[13]; const float* ia_ob = (const float*)d_in[14];
    const float* ta_qw = (const float*)d_in[15]; const float* ta_qb = (const float*)d_in[16];
    const float* ta_kw = (const float*)d_in[17]; const float* ta_kb = (const float*)d_in[18];
    const float* ta_vw = (const float*)d_in[19]; const float* ta_vb = (const float*)d_in[20];
    const float* ta_ow = (const float*)d_in[21]; const float* ta_ob = (const float*)d_in[22];

    const size_t S = (size_t)MDIM * NDIM;          // 524288
    float* ws = (float*)d_ws;
    float* txt = ws + 0 * S;
    float* img = ws + 1 * S;
    float* Qi  = ws + 2 * S;
    float* Ki  = ws + 3 * S;
    float* Vi  = ws + 4 * S;
    float* Qt  = ws + 5 * S;
    float* Kt  = ws + 6 * S;
    float* Vt  = ws + 7 * S;
    bf16* bb     = (bf16*)(ws + 8 * S);
    bf16* capsb  = bb;               // 512*768
    bf16* imgsb  = capsb + 393216;   // 512*1024
    bf16* txtb   = imgsb + S;
    bf16* imgb   = txtb + S;
    bf16* Oib    = imgb + S;
    bf16* Otb    = Oib + S;
    bf16* tp_wb  = Otb + S;          // 1024*768
    bf16* ip_wb  = tp_wb + 786432;
    bf16* qwb[8];
    { bf16* p = ip_wb + 1048576;
      for (int i = 0; i < 8; ++i) { qwb[i] = p; p += 1048576; } }

    float* fused_img = (float*)d_out;
    float* fused_txt = (float*)d_out + S;

    // barrier counters far past used workspace (~43 MB used)
    unsigned* bar = (unsigned*)((char*)d_ws + (64u << 20));

    FusedArgs fa = {};
    fa.cv[0]  = {caps,   capsb, 393216};
    fa.cv[1]  = {images, imgsb, (int)S};
    fa.cv[2]  = {tp_w,   tp_wb, 786432};
    fa.cv[3]  = {ip_w,   ip_wb, 1048576};
    fa.cv[4]  = {ia_qw, qwb[0], 1048576};
    fa.cv[5]  = {ia_kw, qwb[1], 1048576};
    fa.cv[6]  = {ia_vw, qwb[2], 1048576};
    fa.cv[7]  = {ia_ow, qwb[3], 1048576};
    fa.cv[8]  = {ta_qw, qwb[4], 1048576};
    fa.cv[9]  = {ta_kw, qwb[5], 1048576};
    fa.cv[10] = {ta_vw, qwb[6], 1048576};
    fa.cv[11] = {ta_ow, qwb[7], 1048576};

    fa.s1[0] = {capsb, tp_wb, tp_b, nullptr, txt, txtb, 768};
    fa.s1[1] = {imgsb, ip_wb, ip_b, nullptr, img, imgb, 1024};

    fa.s2[0] = {imgb, qwb[0], ia_qb, nullptr, Qi, nullptr, 1024};
    fa.s2[1] = {txtb, qwb[1], ia_kb, nullptr, Ki, nullptr, 1024};
    fa.s2[2] = {txtb, qwb[2], ia_vb, nullptr, Vi, nullptr, 1024};
    fa.s2[3] = {txtb, qwb[4], ta_qb, nullptr, Qt, nullptr, 1024};
    fa.s2[4] = {imgb, qwb[5], ta_kb, nullptr, Kt, nullptr, 1024};
    fa.s2[5] = {imgb, qwb[6], ta_vb, nullptr, Vt, nullptr, 1024};

    fa.at[0] = {Qi, Ki, Vi, ia_kb, ia_vb, Oib};
    fa.at[1] = {Qt, Kt, Vt, ta_kb, ta_vb, Otb};

    fa.s4[0] = {Oib, qwb[3], ia_ob, img, fused_img, nullptr, 1024};
    fa.s4[1] = {Otb, qwb[7], ta_ob, txt, fused_txt, nullptr, 1024};

    fa.bar = bar;

    hipMemsetAsync(bar, 0, 64, stream);
    fused<<<dim3(NBLK), dim3(512), 0, stream>>>(fa);
}

// Round 9
// 206.213 us; speedup vs baseline: 2.6533x; 1.8985x over previous
//
#include <hip/hip_runtime.h>
#include <hip/hip_bf16.h>

// B=1, N_PATCH=N_TOK=512, D_MODEL=1024, HEADS=8 (dh=128), WINDOW=64 -> L=66.
// Multi-kernel (round-5 skeleton) with 128x128-tile GEMM:
// 64^2 tiles staged 256KB per 16KB output (16:1) -> 317MB aggregate staging traffic
// (measured via the fused kernel's 433MB). 128^2 tiles halve that, and m-major
// tile order puts the 4 m-tiles sharing a W-panel on the SAME XCD (stride-8
// blockIdx -> same XCD under round-robin dispatch) so W stays L2-resident.
#define MDIM 512
#define NDIM 1024
#define LSLOT 66

typedef __attribute__((ext_vector_type(8))) short short8;   // 8 bf16 = 4 VGPR
typedef __attribute__((ext_vector_type(4))) short short4v;  // 4 bf16 = 8 B
typedef __attribute__((ext_vector_type(4))) float f32x4;    // MFMA C/D
typedef __hip_bfloat16 bf16;

static __device__ __forceinline__ short f2bf(float f) {
    return __builtin_bit_cast(short, __float2bfloat16(f));
}
static __device__ __forceinline__ short8 cvt8(float4 a, float4 b) {
    short8 v;
    v[0] = f2bf(a.x); v[1] = f2bf(a.y); v[2] = f2bf(a.z); v[3] = f2bf(a.w);
    v[4] = f2bf(b.x); v[5] = f2bf(b.y); v[6] = f2bf(b.z); v[7] = f2bf(b.w);
    return v;
}
// async 16B global -> LDS DMA. LDS dest = uniform base + lane*16.
static __device__ __forceinline__ void gload16(const void* g, void* l) {
    __builtin_amdgcn_global_load_lds(
        (const __attribute__((address_space(1))) unsigned int*)g,
        (__attribute__((address_space(3))) unsigned int*)l, 16, 0, 0);
}

// ---------------- prep: fp32 -> bf16 conversions ----------------
struct CvtDesc { const float* src; bf16* dst; int n; };
struct CvtBatch { CvtDesc d[12]; };

__global__ __launch_bounds__(256) void cvt_bf16(CvtBatch cb) {
    CvtDesc c = cb.d[blockIdx.z];
    const int i = (blockIdx.x * 256 + threadIdx.x) * 8;
    if (i >= c.n) return;
    const float4 a = *(const float4*)(c.src + i);
    const float4 b = *(const float4*)(c.src + i + 4);
    *(short8*)((short*)c.dst + i) = cvt8(a, b);
}

// ---------------- bf16 MFMA GEMM: 128x128 tile, 4 waves, BK=64 ----------------
// C = A @ W^T + bias (+res). Wave w=(wr<<1)|wc owns the 64x64 quadrant (wr,wc):
// acc[4][4] of 16x16 frags, 32 MFMA : 16 ds_read_b128 per K-step.
// Staging: waves 0,1 DMA the A half-rows, waves 2,3 the W half-rows (8 gload16
// each per K-tile). 2 LDS buffers x 32KB = 64KB -> 2 blocks/CU. Counted
// vmcnt(8) keeps the next tile's 8 loads/wave in flight across the barrier.
// LDS swizzle (both-sides XOR, rule #21): 16B chunk s of row r holds global
// k-chunk s^(r&7); linear DMA dest + inverse-swizzled per-lane global source.
struct GDesc {
    const bf16* A;      // (512, K)
    const bf16* W;      // (1024, K)
    const float* bias;  // (1024)
    const float* res;   // optional fp32 residual or nullptr
    float* C;           // fp32 out (512,1024)
    bf16* Cb;           // optional bf16 dual-out or nullptr
    int K;              // 768 or 1024 (multiple of 64, NT>=2)
};
struct GBatch { GDesc d[6]; };

__global__ __launch_bounds__(256, 2) void gemm_bf16(GBatch gb) {
    GDesc g = gb.d[blockIdx.y];
    const int K = g.K;
    __shared__ __align__(16) char smem[65536];   // [buf:2][A 16KB | W 16KB]

    const int tid  = threadIdx.x;
    const int lane = tid & 63;
    const int wave = tid >> 6;          // 0..3
    const int wr = wave >> 1, wc = wave & 1;
    const int tile = blockIdx.x;        // 0..31, m-major: m = tile>>3, n = tile&7
    const int m0 = (tile >> 3) * 128;
    const int n0 = (tile & 7) * 128;

    // staging role: waves 0,1 stage A rows [half*64,..+64); waves 2,3 stage W.
    const int isW  = wave >> 1;
    const int half = wave & 1;
    const size_t rowb = (size_t)K * 2;
    const char* sbase = (const char*)(isW ? (const void*)g.W : (const void*)g.A)
                      + (size_t)((isW ? n0 : m0) + half * 64 + (lane >> 3)) * rowb
                      + (size_t)(((lane & 7) ^ (lane >> 3)) << 4);
    const int dbase = isW * 16384 + half * 8192 + lane * 16;   // byte offset in buf

    const int fr = lane & 15;
    const int fq = lane >> 4;           // 0..3

    f32x4 acc[4][4] = {};
    const int NT = K / 64;

    // prologue: tiles 0,1 -> bufs 0,1 (16 loads/wave in flight)
#pragma unroll
    for (int tt = 0; tt < 2; ++tt)
#pragma unroll
        for (int i = 0; i < 8; ++i)
            gload16(sbase + (size_t)tt * 128 + (size_t)i * 8 * rowb,
                    smem + tt * 32768 + dbase + i * 1024);

#define GSTEP(VMW)                                                              \
    {                                                                           \
        asm volatile("s_waitcnt vmcnt(" #VMW ")" ::: "memory");                 \
        __builtin_amdgcn_s_barrier();        /* tile t resident (all waves) */  \
        __builtin_amdgcn_sched_barrier(0);                                      \
        const char* Lb = smem + (t & 1) * 32768;                                \
        short8 af[4][2], wf[4][2];                                              \
        _Pragma("unroll")                                                       \
        for (int kk = 0; kk < 2; ++kk) {                                        \
            const int ch = kk * 4 + fq;                                         \
            const int sw = (ch ^ (fr & 7)) << 4;                                \
            _Pragma("unroll")                                                   \
            for (int fi = 0; fi < 4; ++fi) {                                    \
                const int ra = wr * 64 + fi * 16 + fr;                          \
                af[fi][kk] = *(const short8*)(Lb + ra * 128 + sw);              \
                const int rw = wc * 64 + fi * 16 + fr;                          \
                wf[fi][kk] = *(const short8*)(Lb + 16384 + rw * 128 + sw);      \
            }                                                                   \
        }                                                                       \
        asm volatile("s_waitcnt lgkmcnt(0)" ::: "memory");                      \
        __builtin_amdgcn_sched_barrier(0);                                      \
        __builtin_amdgcn_s_barrier();        /* all reads of buf done */        \
        if (t + 2 < NT) {                                                       \
            const char* p = sbase + (size_t)(t + 2) * 128;                      \
            char* d = smem + (t & 1) * 32768 + dbase;                           \
            _Pragma("unroll")                                                   \
            for (int i = 0; i < 8; ++i)                                         \
                gload16(p + (size_t)i * 8 * rowb, d + i * 1024);                \
        }                                                                       \
        _Pragma("unroll")                                                       \
        for (int kk = 0; kk < 2; ++kk)                                          \
            _Pragma("unroll")                                                   \
            for (int fi = 0; fi < 4; ++fi)                                      \
                _Pragma("unroll")                                               \
                for (int fj = 0; fj < 4; ++fj)                                  \
                    acc[fi][fj] = __builtin_amdgcn_mfma_f32_16x16x32_bf16(      \
                        af[fi][kk], wf[fj][kk], acc[fi][fj], 0, 0, 0);          \
    }

    int t = 0;
    for (; t < NT - 1; ++t) GSTEP(8)    // tile t+1 stays in flight
    GSTEP(0)                            // last tile: drain
#undef GSTEP

    // epilogue: C/D layout col=lane&15, row=(lane>>4)*4+reg
#pragma unroll
    for (int fi = 0; fi < 4; ++fi) {
        const int row0 = m0 + wr * 64 + fi * 16 + fq * 4;
#pragma unroll
        for (int fj = 0; fj < 4; ++fj) {
            const int col = n0 + wc * 64 + fj * 16 + fr;
            const float b = g.bias[col];
#pragma unroll
            for (int r = 0; r < 4; ++r) {
                float v = acc[fi][fj][r] + b;
                const size_t o = (size_t)(row0 + r) * NDIM + col;
                if (g.res) v += g.res[o];
                g.C[o] = v;
                if (g.Cb) g.Cb[o] = __float2bfloat16(v);
            }
        }
    }
}

// ---------------- sliding-window attention (unchanged, round-5 validated) ------
struct AttnArgs {
    const float *Q, *K, *V, *kb, *vb;
    bf16* O;   // bf16 out -> feeds stage-4 GEMM A directly
};

__global__ __launch_bounds__(256) void attn_tile(AttnArgs a0, AttnArgs a1) {
    const AttnArgs a = blockIdx.z ? a1 : a0;
    const int h  = blockIdx.y;
    const int n0 = blockIdx.x * 32;
    const int tid = threadIdx.x;

    __shared__ float Ks[97 * 128];
    __shared__ float Vs[97 * 128];
    __shared__ float Qs[32 * 132];
    __shared__ float Ps[32 * 68];
    __shared__ float InvS[32];

    for (int i = tid; i < 97 * 32; i += 256) {
        const int wp = i >> 5, d4 = i & 31;
        const int idx = n0 - 32 + wp;
        const bool valid = (idx >= 0) && (idx < MDIM);
        const float* sk = (valid ? (a.K + (size_t)idx * NDIM) : a.kb) + h * 128;
        const float* sv = (valid ? (a.V + (size_t)idx * NDIM) : a.vb) + h * 128;
        const float4 kv = *(const float4*)(sk + d4 * 4);
        const float4 vv = *(const float4*)(sv + d4 * 4);
        const int slot = d4 ^ (wp & 31);
        *(float4*)&Ks[wp * 128 + slot * 4] = kv;
        *(float4*)&Vs[wp * 128 + slot * 4] = vv;
    }
    for (int i = tid; i < 32 * 32; i += 256) {
        const int r = i >> 5, d4 = i & 31;
        *(float4*)&Qs[r * 132 + d4 * 4] =
            *(const float4*)(a.Q + (size_t)(n0 + r) * NDIM + h * 128 + d4 * 4);
    }
    __syncthreads();

    const int r = tid >> 3, sub = tid & 7;
    const int n = n0 + r;
    const int lo_inv = max(0, 32 - n);
    const int hi_inv = max(0, n - 478);
    const int n_zero = max(0, 64 - (LSLOT - lo_inv - hi_inv));
    const float scale = 0.088388347648318447f;  // 1/sqrt(128)

    float dots[9];
#pragma unroll
    for (int k = 0; k < 9; ++k) dots[k] = 0.f;
#pragma unroll
    for (int db = 0; db < 4; ++db) {
        float4 q[8];
#pragma unroll
        for (int c = 0; c < 8; ++c) q[c] = *(float4*)&Qs[r * 132 + (db * 8 + c) * 4];
        for (int k = 0; k < 9; ++k) {
            const int l = sub + 8 * k;
            if (l >= LSLOT) break;
            const int wp = r + l, key = wp & 31;
            float accd = dots[k];
#pragma unroll
            for (int c = 0; c < 8; ++c) {
                const int d4 = db * 8 + c;
                const float4 kv = *(float4*)&Ks[wp * 128 + (d4 ^ key) * 4];
                accd += kv.x * q[c].x + kv.y * q[c].y + kv.z * q[c].z + kv.w * q[c].w;
            }
            dots[k] = accd;
        }
    }
    for (int k = 0; k < 9; ++k) {
        const int l = sub + 8 * k;
        if (l >= LSLOT) break;
        const int idx = n - 32 + l;
        const bool valid = (idx >= 0) && (idx < MDIM);
        bool attend = valid;
        if (!valid) {
            const int ir = (l < lo_inv) ? l : (l - (LSLOT - hi_inv));
            attend = ir < n_zero;
        }
        Ps[r * 68 + l] = attend ? dots[k] * scale : -1e30f;
    }
    __syncthreads();

    {
        float m = -1e30f;
        for (int k = 0; k < 9; ++k) {
            const int l = sub + 8 * k;
            if (l < LSLOT) m = fmaxf(m, Ps[r * 68 + l]);
        }
        for (int s = 1; s < 8; s <<= 1) m = fmaxf(m, __shfl_xor(m, s, 64));
        float sum = 0.f;
        for (int k = 0; k < 9; ++k) {
            const int l = sub + 8 * k;
            if (l >= LSLOT) break;
            const float e = expf(Ps[r * 68 + l] - m);
            Ps[r * 68 + l] = e;
            sum += e;
        }
        for (int s = 1; s < 8; s <<= 1) sum += __shfl_xor(sum, s, 64);
        if (sub == 0) InvS[r] = 1.0f / sum;
    }
    __syncthreads();

    float4 acc[4] = {};
    for (int l = 0; l < LSLOT; ++l) {
        const float p = Ps[r * 68 + l];
        const int wp = r + l, key = wp & 31;
#pragma unroll
        for (int c = 0; c < 4; ++c) {
            const int d4 = sub + 8 * c;
            const float4 vv = *(float4*)&Vs[wp * 128 + (d4 ^ key) * 4];
            acc[c].x += p * vv.x; acc[c].y += p * vv.y;
            acc[c].z += p * vv.z; acc[c].w += p * vv.w;
        }
    }
    const float inv = InvS[r];
#pragma unroll
    for (int c = 0; c < 4; ++c) {
        short4v o;
        o[0] = f2bf(acc[c].x * inv); o[1] = f2bf(acc[c].y * inv);
        o[2] = f2bf(acc[c].z * inv); o[3] = f2bf(acc[c].w * inv);
        *(short4v*)((short*)a.O + (size_t)n * NDIM + h * 128 + (sub + 8 * c) * 4) = o;
    }
}

extern "C" void kernel_launch(void* const* d_in, const int* in_sizes, int n_in,
                              void* d_out, int out_size, void* d_ws, size_t ws_size,
                              hipStream_t stream) {
    const float* images = (const float*)d_in[0];   // (512,1024)
    const float* caps   = (const float*)d_in[1];   // (512,768)
    const float* tp_w = (const float*)d_in[3];
    const float* tp_b = (const float*)d_in[4];
    const float* ip_w = (const float*)d_in[5];
    const float* ip_b = (const float*)d_in[6];
    const float* ia_qw = (const float*)d_in[7];  const float* ia_qb = (const float*)d_in[8];
    const float* ia_kw = (const float*)d_in[9];  const float* ia_kb = (const float*)d_in[10];
    const float* ia_vw = (const float*)d_in[11]; const float* ia_vb = (const float*)d_in[12];
    const float* ia_ow = (const float*)d_in[13]; const float* ia_ob = (const float*)d_in[14];
    const float* ta_qw = (const float*)d_in[15]; const float* ta_qb = (const float*)d_in[16];
    const float* ta_kw = (const float*)d_in[17]; const float* ta_kb = (const float*)d_in[18];
    const float* ta_vw = (const float*)d_in[19]; const float* ta_vb = (const float*)d_in[20];
    const float* ta_ow = (const float*)d_in[21]; const float* ta_ob = (const float*)d_in[22];

    const size_t S = (size_t)MDIM * NDIM;          // 524288
    float* ws = (float*)d_ws;
    float* txt = ws + 0 * S;
    float* img = ws + 1 * S;
    float* Qi  = ws + 2 * S;
    float* Ki  = ws + 3 * S;
    float* Vi  = ws + 4 * S;
    float* Qt  = ws + 5 * S;
    float* Kt  = ws + 6 * S;
    float* Vt  = ws + 7 * S;
    bf16* bb     = (bf16*)(ws + 8 * S);
    bf16* capsb  = bb;               // 512*768
    bf16* imgsb  = capsb + 393216;   // 512*1024
    bf16* txtb   = imgsb + S;
    bf16* imgb   = txtb + S;
    bf16* Oib    = imgb + S;
    bf16* Otb    = Oib + S;
    bf16* tp_wb  = Otb + S;          // 1024*768
    bf16* ip_wb  = tp_wb + 786432;
    bf16* qwb[8];
    { bf16* p = ip_wb + 1048576;
      for (int i = 0; i < 8; ++i) { qwb[i] = p; p += 1048576; } }

    float* fused_img = (float*)d_out;
    float* fused_txt = (float*)d_out + S;

    // ---- prep: convert inputs + weights to bf16 ----
    CvtBatch cv = {};
    cv.d[0]  = {caps,   capsb, 393216};
    cv.d[1]  = {images, imgsb, (int)S};
    cv.d[2]  = {tp_w,   tp_wb, 786432};
    cv.d[3]  = {ip_w,   ip_wb, 1048576};
    cv.d[4]  = {ia_qw, qwb[0], 1048576};
    cv.d[5]  = {ia_kw, qwb[1], 1048576};
    cv.d[6]  = {ia_vw, qwb[2], 1048576};
    cv.d[7]  = {ia_ow, qwb[3], 1048576};
    cv.d[8]  = {ta_qw, qwb[4], 1048576};
    cv.d[9]  = {ta_kw, qwb[5], 1048576};
    cv.d[10] = {ta_vw, qwb[6], 1048576};
    cv.d[11] = {ta_ow, qwb[7], 1048576};
    cvt_bf16<<<dim3(512, 1, 12), 256, 0, stream>>>(cv);

    dim3 blk(256);

    // ---- stage 1: input projections (dual fp32 + bf16 out); 32 tiles/gemm ----
    GBatch b1 = {};
    b1.d[0] = {capsb, tp_wb, tp_b, nullptr, txt, txtb, 768};
    b1.d[1] = {imgsb, ip_wb, ip_b, nullptr, img, imgb, 1024};
    gemm_bf16<<<dim3(32, 2), blk, 0, stream>>>(b1);

    // ---- stage 2: QKV (fp32 out for attn) ----
    GBatch b2 = {};
    b2.d[0] = {imgb, qwb[0], ia_qb, nullptr, Qi, nullptr, 1024};
    b2.d[1] = {txtb, qwb[1], ia_kb, nullptr, Ki, nullptr, 1024};
    b2.d[2] = {txtb, qwb[2], ia_vb, nullptr, Vi, nullptr, 1024};
    b2.d[3] = {txtb, qwb[4], ta_qb, nullptr, Qt, nullptr, 1024};
    b2.d[4] = {imgb, qwb[5], ta_kb, nullptr, Kt, nullptr, 1024};
    b2.d[5] = {imgb, qwb[6], ta_vb, nullptr, Vt, nullptr, 1024};
    gemm_bf16<<<dim3(32, 6), blk, 0, stream>>>(b2);

    // ---- stage 3: attention (bf16 O out) ----
    AttnArgs aa = {Qi, Ki, Vi, ia_kb, ia_vb, Oib};
    AttnArgs ab = {Qt, Kt, Vt, ta_kb, ta_vb, Otb};
    attn_tile<<<dim3(16, 8, 2), 256, 0, stream>>>(aa, ab);

    // ---- stage 4: output projections + residual ----
    GBatch b4 = {};
    b4.d[0] = {Oib, qwb[3], ia_ob, img, fused_img, nullptr, 1024};
    b4.d[1] = {Otb, qwb[7], ta_ob, txt, fused_txt, nullptr, 1024};
    gemm_bf16<<<dim3(32, 2), blk, 0, stream>>>(b4);
}

// Round 10
// 198.616 us; speedup vs baseline: 2.7548x; 1.0383x over previous
//
#include <hip/hip_runtime.h>
#include <hip/hip_bf16.h>

// B=1, N_PATCH=N_TOK=512, D_MODEL=1024, HEADS=8 (dh=128), WINDOW=64 -> L=66.
// Round-5 structure (best: 179.8us) with ONE change: attn no longer stages V in
// LDS (V is L2/L3-hot from stage 2; staging it cost 50KB LDS and held the kernel
// at 1 block/CU). LDS 125KB -> 75KB => 2 blocks/CU, 8 waves/CU during attention.
#define MDIM 512
#define NDIM 1024
#define LSLOT 66

typedef __attribute__((ext_vector_type(8))) short short8;   // 8 bf16 = 4 VGPR
typedef __attribute__((ext_vector_type(4))) short short4v;  // 4 bf16 = 8 B
typedef __attribute__((ext_vector_type(4))) float f32x4;    // MFMA C/D
typedef __hip_bfloat16 bf16;

static __device__ __forceinline__ short f2bf(float f) {
    return __builtin_bit_cast(short, __float2bfloat16(f));
}
static __device__ __forceinline__ short8 cvt8(float4 a, float4 b) {
    short8 v;
    v[0] = f2bf(a.x); v[1] = f2bf(a.y); v[2] = f2bf(a.z); v[3] = f2bf(a.w);
    v[4] = f2bf(b.x); v[5] = f2bf(b.y); v[6] = f2bf(b.z); v[7] = f2bf(b.w);
    return v;
}

// async 16B global -> LDS DMA. LDS dest = uniform base + lane*16.
static __device__ __forceinline__ void gload16(const void* g, void* l) {
    __builtin_amdgcn_global_load_lds(
        (const __attribute__((address_space(1))) unsigned int*)g,
        (__attribute__((address_space(3))) unsigned int*)l, 16, 0, 0);
}

// ---------------- prep: fp32 -> bf16 conversions ----------------
struct CvtDesc { const float* src; bf16* dst; int n; };
struct CvtBatch { CvtDesc d[12]; };

__global__ __launch_bounds__(256) void cvt_bf16(CvtBatch cb) {
    CvtDesc c = cb.d[blockIdx.z];
    const int i = (blockIdx.x * 256 + threadIdx.x) * 8;
    if (i >= c.n) return;
    const float4 a = *(const float4*)(c.src + i);
    const float4 b = *(const float4*)(c.src + i + 4);
    *(short8*)((short*)c.dst + i) = cvt8(a, b);
}

// ---------------- bf16 MFMA GEMM, 3-deep counted-vmcnt pipeline (round-5) -------
// C = A @ W^T + bias (+res). Tile 64x64, BK=64, 2 waves (wave w: rows [w*32,w*32+32)
// x 64 cols). 3 LDS buffers (48 KB -> 3 blocks/CU); tile t in buf t%3; loads for
// t+3 issued after all reads of buf t%3 complete. Main-loop wait vmcnt(16) (2 tiles
// = 16 loads/wave stay in flight); tail peels 8 then 0.
// LDS swizzle (both-sides XOR, rule #21): chunk s of row r holds global k-chunk
// s^(r&7); staged with linear LDS dest + inverse-swizzled per-lane global source.
struct GDesc {
    const bf16* A;      // (512, K)
    const bf16* W;      // (1024, K)
    const float* bias;  // (1024)
    const float* res;   // optional fp32 residual or nullptr
    float* C;           // fp32 out (512,1024)
    bf16* Cb;           // optional bf16 dual-out or nullptr
    int K;              // multiple of 64 (768 or 1024 here -> NT 12 or 16)
};
struct GBatch { GDesc d[6]; };

__global__ __launch_bounds__(128) void gemm_bf16(GBatch gb) {
    GDesc g = gb.d[blockIdx.z];
    const int K = g.K;
    __shared__ __align__(16) short lds[3][2][64 * 64];  // [buf][0=A,1=W] 48 KB

    const int tid  = threadIdx.x;
    const int lane = tid & 63;
    const int wave = tid >> 6;          // wave0 stages A-half, wave1 stages W-half
    const int m0 = blockIdx.y * 64;
    const int n0 = blockIdx.x * 64;
    const int wm = wave * 32;

    // staging source: lane l fetches (row = i*8 + (l>>3), kchunk = (l&7)^(l>>3))
    const size_t rowb = (size_t)K * 2;  // row stride bytes
    const char* sbase = (const char*)(wave ? (const void*)g.W : (const void*)g.A)
                      + (size_t)(wave ? n0 : m0) * rowb
                      + (size_t)(lane >> 3) * rowb
                      + (size_t)(((lane & 7) ^ (lane >> 3)) << 4);

    const int fr = lane & 15;
    const int fq = lane >> 4;           // 0..3

    f32x4 acc[2][4] = {};
    const int NT = K / 64;              // >= 4 assumed

    // prologue: issue tiles 0,1,2 into bufs 0,1,2 (24 loads/wave outstanding)
#pragma unroll
    for (int tt = 0; tt < 3; ++tt)
#pragma unroll
        for (int i = 0; i < 8; ++i)
            gload16(sbase + (size_t)tt * 128 + (size_t)i * 8 * rowb,
                    &lds[tt][wave][i * 512]);

#define GSTEP(VMW)                                                              \
    {                                                                           \
        asm volatile("s_waitcnt vmcnt(" #VMW ")" ::: "memory");                 \
        __builtin_amdgcn_s_barrier();        /* tile t resident, both halves */ \
        __builtin_amdgcn_sched_barrier(0);                                      \
        const int b = t % 3;                                                    \
        short8 af[2][2], wf[4][2];                                              \
        _Pragma("unroll")                                                       \
        for (int kk = 0; kk < 2; ++kk) {                                        \
            const int ch = kk * 4 + fq;                                         \
            _Pragma("unroll")                                                   \
            for (int i = 0; i < 2; ++i) {                                       \
                const int r = wm + i * 16 + fr;                                 \
                af[i][kk] = *(const short8*)&lds[b][0][r * 64 + ((ch ^ (r & 7)) << 3)]; \
            }                                                                   \
            _Pragma("unroll")                                                   \
            for (int j = 0; j < 4; ++j) {                                       \
                const int c = j * 16 + fr;                                      \
                wf[j][kk] = *(const short8*)&lds[b][1][c * 64 + ((ch ^ (c & 7)) << 3)]; \
            }                                                                   \
        }                                                                       \
        asm volatile("s_waitcnt lgkmcnt(0)" ::: "memory");                      \
        __builtin_amdgcn_sched_barrier(0);                                      \
        __builtin_amdgcn_s_barrier();        /* all reads of buf b done */      \
        if (t + 3 < NT) {                                                       \
            const char* p = sbase + (size_t)(t + 3) * 128;                      \
            _Pragma("unroll")                                                   \
            for (int i = 0; i < 8; ++i)                                         \
                gload16(p + (size_t)i * 8 * rowb, &lds[b][wave][i * 512]);      \
        }                                                                       \
        _Pragma("unroll")                                                       \
        for (int kk = 0; kk < 2; ++kk)                                          \
            _Pragma("unroll")                                                   \
            for (int i = 0; i < 2; ++i)                                         \
                _Pragma("unroll")                                               \
                for (int j = 0; j < 4; ++j)                                     \
                    acc[i][j] = __builtin_amdgcn_mfma_f32_16x16x32_bf16(        \
                        af[i][kk], wf[j][kk], acc[i][j], 0, 0, 0);              \
    }

    int t = 0;
    for (; t < NT - 2; ++t) GSTEP(16)   // tiles t+1,t+2 stay in flight
    GSTEP(8)                            // t = NT-2: only t+1 in flight
    ++t;
    GSTEP(0)                            // t = NT-1: drain
#undef GSTEP

    // epilogue: C/D layout col=lane&15, row=(lane>>4)*4+reg
#pragma unroll
    for (int i = 0; i < 2; ++i) {
        const int row0 = m0 + wm + i * 16 + fq * 4;
#pragma unroll
        for (int j = 0; j < 4; ++j) {
            const int col = n0 + j * 16 + fr;
            const float b = g.bias[col];
#pragma unroll
            for (int r = 0; r < 4; ++r) {
                float v = acc[i][j][r] + b;
                const size_t o = (size_t)(row0 + r) * NDIM + col;
                if (g.res) v += g.res[o];
                g.C[o] = v;
                if (g.Cb) g.Cb[o] = __float2bfloat16(v);
            }
        }
    }
}

// ---------------- sliding-window attention ----------------
struct AttnArgs {
    const float *Q, *K, *V, *kb, *vb;
    bf16* O;   // bf16 out -> feeds stage-4 GEMM A directly
};

// block = (32 query rows) x (1 head) x (1 attn); grid (16,8,2), 256 threads.
// K window staged in LDS (needed for the 8-lane-per-row dot pattern); V read
// directly from global in the PV loop (L2/L3-hot from stage 2) -> LDS 75 KB,
// 2 blocks/CU.
__global__ __launch_bounds__(256) void attn_tile(AttnArgs a0, AttnArgs a1) {
    const AttnArgs a = blockIdx.z ? a1 : a0;
    const int h  = blockIdx.y;
    const int n0 = blockIdx.x * 32;
    const int tid = threadIdx.x;

    __shared__ float Ks[97 * 128];
    __shared__ float Qs[32 * 132];
    __shared__ float Ps[32 * 68];
    __shared__ float InvS[32];

    // stage K window rows wp=0..96 (ctx rows n0-32 .. n0+64); OOB -> kb
    for (int i = tid; i < 97 * 32; i += 256) {
        const int wp = i >> 5, d4 = i & 31;
        const int idx = n0 - 32 + wp;
        const bool valid = (idx >= 0) && (idx < MDIM);
        const float* sk = (valid ? (a.K + (size_t)idx * NDIM) : a.kb) + h * 128;
        const float4 kv = *(const float4*)(sk + d4 * 4);
        const int slot = d4 ^ (wp & 31);
        *(float4*)&Ks[wp * 128 + slot * 4] = kv;
    }
    for (int i = tid; i < 32 * 32; i += 256) {
        const int r = i >> 5, d4 = i & 31;
        *(float4*)&Qs[r * 132 + d4 * 4] =
            *(const float4*)(a.Q + (size_t)(n0 + r) * NDIM + h * 128 + d4 * 4);
    }
    __syncthreads();

    const int r = tid >> 3, sub = tid & 7;
    const int n = n0 + r;
    const int lo_inv = max(0, 32 - n);
    const int hi_inv = max(0, n - 478);
    const int n_zero = max(0, 64 - (LSLOT - lo_inv - hi_inv));
    const float scale = 0.088388347648318447f;  // 1/sqrt(128)

    float dots[9];
#pragma unroll
    for (int k = 0; k < 9; ++k) dots[k] = 0.f;
#pragma unroll
    for (int db = 0; db < 4; ++db) {
        float4 q[8];
#pragma unroll
        for (int c = 0; c < 8; ++c) q[c] = *(float4*)&Qs[r * 132 + (db * 8 + c) * 4];
        for (int k = 0; k < 9; ++k) {
            const int l = sub + 8 * k;
            if (l >= LSLOT) break;
            const int wp = r + l, key = wp & 31;
            float accd = dots[k];
#pragma unroll
            for (int c = 0; c < 8; ++c) {
                const int d4 = db * 8 + c;
                const float4 kv = *(float4*)&Ks[wp * 128 + (d4 ^ key) * 4];
                accd += kv.x * q[c].x + kv.y * q[c].y + kv.z * q[c].z + kv.w * q[c].w;
            }
            dots[k] = accd;
        }
    }
    for (int k = 0; k < 9; ++k) {
        const int l = sub + 8 * k;
        if (l >= LSLOT) break;
        const int idx = n - 32 + l;
        const bool valid = (idx >= 0) && (idx < MDIM);
        bool attend = valid;
        if (!valid) {
            const int ir = (l < lo_inv) ? l : (l - (LSLOT - hi_inv));
            attend = ir < n_zero;
        }
        Ps[r * 68 + l] = attend ? dots[k] * scale : -1e30f;
    }
    __syncthreads();

    {
        float m = -1e30f;
        for (int k = 0; k < 9; ++k) {
            const int l = sub + 8 * k;
            if (l < LSLOT) m = fmaxf(m, Ps[r * 68 + l]);
        }
        for (int s = 1; s < 8; s <<= 1) m = fmaxf(m, __shfl_xor(m, s, 64));
        float sum = 0.f;
        for (int k = 0; k < 9; ++k) {
            const int l = sub + 8 * k;
            if (l >= LSLOT) break;
            const float e = expf(Ps[r * 68 + l] - m);
            Ps[r * 68 + l] = e;
            sum += e;
        }
        for (int s = 1; s < 8; s <<= 1) sum += __shfl_xor(sum, s, 64);
        if (sub == 0) InvS[r] = 1.0f / sum;
    }
    __syncthreads();

    // PV: thread (r,sub) owns d4 chunks sub, sub+8, sub+16, sub+24.
    // V rows read directly from global (L2-hot); bit-identical values/order to
    // the staged version.
    float4 acc[4] = {};
    for (int l = 0; l < LSLOT; ++l) {
        const float p = Ps[r * 68 + l];
        if (p != 0.f) {
            const int idx = n - 32 + l;
            const bool valid = (idx >= 0) && (idx < MDIM);
            const float* vrow = (valid ? (a.V + (size_t)idx * NDIM) : a.vb) + h * 128;
#pragma unroll
            for (int c = 0; c < 4; ++c) {
                const float4 vv = *(const float4*)(vrow + (sub + 8 * c) * 4);
                acc[c].x += p * vv.x; acc[c].y += p * vv.y;
                acc[c].z += p * vv.z; acc[c].w += p * vv.w;
            }
        }
    }
    const float inv = InvS[r];
#pragma unroll
    for (int c = 0; c < 4; ++c) {
        short4v o;
        o[0] = f2bf(acc[c].x * inv); o[1] = f2bf(acc[c].y * inv);
        o[2] = f2bf(acc[c].z * inv); o[3] = f2bf(acc[c].w * inv);
        *(short4v*)((short*)a.O + (size_t)n * NDIM + h * 128 + (sub + 8 * c) * 4) = o;
    }
}

extern "C" void kernel_launch(void* const* d_in, const int* in_sizes, int n_in,
                              void* d_out, int out_size, void* d_ws, size_t ws_size,
                              hipStream_t stream) {
    const float* images = (const float*)d_in[0];   // (512,1024)
    const float* caps   = (const float*)d_in[1];   // (512,768)
    const float* tp_w = (const float*)d_in[3];
    const float* tp_b = (const float*)d_in[4];
    const float* ip_w = (const float*)d_in[5];
    const float* ip_b = (const float*)d_in[6];
    const float* ia_qw = (const float*)d_in[7];  const float* ia_qb = (const float*)d_in[8];
    const float* ia_kw = (const float*)d_in[9];  const float* ia_kb = (const float*)d_in[10];
    const float* ia_vw = (const float*)d_in[11]; const float* ia_vb = (const float*)d_in[12];
    const float* ia_ow = (const float*)d_in[13]; const float* ia_ob = (const float*)d_in[14];
    const float* ta_qw = (const float*)d_in[15]; const float* ta_qb = (const float*)d_in[16];
    const float* ta_kw = (const float*)d_in[17]; const float* ta_kb = (const float*)d_in[18];
    const float* ta_vw = (const float*)d_in[19]; const float* ta_vb = (const float*)d_in[20];
    const float* ta_ow = (const float*)d_in[21]; const float* ta_ob = (const float*)d_in[22];

    const size_t S = (size_t)MDIM * NDIM;          // 524288
    float* ws = (float*)d_ws;
    float* txt = ws + 0 * S;
    float* img = ws + 1 * S;
    float* Qi  = ws + 2 * S;
    float* Ki  = ws + 3 * S;
    float* Vi  = ws + 4 * S;
    float* Qt  = ws + 5 * S;
    float* Kt  = ws + 6 * S;
    float* Vt  = ws + 7 * S;
    bf16* bb     = (bf16*)(ws + 8 * S);
    bf16* capsb  = bb;               // 512*768
    bf16* imgsb  = capsb + 393216;   // 512*1024
    bf16* txtb   = imgsb + S;
    bf16* imgb   = txtb + S;
    bf16* Oib    = imgb + S;
    bf16* Otb    = Oib + S;
    bf16* tp_wb  = Otb + S;          // 1024*768
    bf16* ip_wb  = tp_wb + 786432;
    bf16* qwb[8];
    { bf16* p = ip_wb + 1048576;
      for (int i = 0; i < 8; ++i) { qwb[i] = p; p += 1048576; } }

    float* fused_img = (float*)d_out;
    float* fused_txt = (float*)d_out + S;

    // ---- prep: convert inputs + weights to bf16 ----
    CvtBatch cv = {};
    cv.d[0]  = {caps,   capsb, 393216};
    cv.d[1]  = {images, imgsb, (int)S};
    cv.d[2]  = {tp_w,   tp_wb, 786432};
    cv.d[3]  = {ip_w,   ip_wb, 1048576};
    cv.d[4]  = {ia_qw, qwb[0], 1048576};
    cv.d[5]  = {ia_kw, qwb[1], 1048576};
    cv.d[6]  = {ia_vw, qwb[2], 1048576};
    cv.d[7]  = {ia_ow, qwb[3], 1048576};
    cv.d[8]  = {ta_qw, qwb[4], 1048576};
    cv.d[9]  = {ta_kw, qwb[5], 1048576};
    cv.d[10] = {ta_vw, qwb[6], 1048576};
    cv.d[11] = {ta_ow, qwb[7], 1048576};
    cvt_bf16<<<dim3(512, 1, 12), 256, 0, stream>>>(cv);

    dim3 blk(128);
    dim3 tiles(NDIM / 64, MDIM / 64);  // 16 x 8

    // ---- stage 1: input projections (dual fp32 + bf16 out) ----
    GBatch b1 = {};
    b1.d[0] = {capsb, tp_wb, tp_b, nullptr, txt, txtb, 768};
    b1.d[1] = {imgsb, ip_wb, ip_b, nullptr, img, imgb, 1024};
    gemm_bf16<<<dim3(tiles.x, tiles.y, 2), blk, 0, stream>>>(b1);

    // ---- stage 2: QKV (fp32 out for attn) ----
    GBatch b2 = {};
    b2.d[0] = {imgb, qwb[0], ia_qb, nullptr, Qi, nullptr, 1024};
    b2.d[1] = {txtb, qwb[1], ia_kb, nullptr, Ki, nullptr, 1024};
    b2.d[2] = {txtb, qwb[2], ia_vb, nullptr, Vi, nullptr, 1024};
    b2.d[3] = {txtb, qwb[4], ta_qb, nullptr, Qt, nullptr, 1024};
    b2.d[4] = {imgb, qwb[5], ta_kb, nullptr, Kt, nullptr, 1024};
    b2.d[5] = {imgb, qwb[6], ta_vb, nullptr, Vt, nullptr, 1024};
    gemm_bf16<<<dim3(tiles.x, tiles.y, 6), blk, 0, stream>>>(b2);

    // ---- stage 3: attention (bf16 O out) ----
    AttnArgs aa = {Qi, Ki, Vi, ia_kb, ia_vb, Oib};
    AttnArgs ab = {Qt, Kt, Vt, ta_kb, ta_vb, Otb};
    attn_tile<<<dim3(16, 8, 2), 256, 0, stream>>>(aa, ab);

    // ---- stage 4: output projections + residual ----
    GBatch b4 = {};
    b4.d[0] = {Oib, qwb[3], ia_ob, img, fused_img, nullptr, 1024};
    b4.d[1] = {Otb, qwb[7], ta_ob, txt, fused_txt, nullptr, 1024};
    gemm_bf16<<<dim3(tiles.x, tiles.y, 2), blk, 0, stream>>>(b4);
}